// Round 12
// baseline (358.568 us; speedup 1.0000x reference)
//
#include <hip/hip_runtime.h>
#include <hip/hip_bf16.h>

#define LRELU_SLOPE 0.2f

typedef __attribute__((ext_vector_type(8))) short short8;
typedef __attribute__((ext_vector_type(4))) float f32x4;

__device__ __forceinline__ unsigned short bf16r(float f) {
    unsigned int u = __builtin_bit_cast(unsigned int, f);
    u += 0x7fffu + ((u >> 16) & 1u);   // RNE
    return (unsigned short)(u >> 16);
}
__device__ __forceinline__ float bf2f(unsigned short u) {
    return __builtin_bit_cast(float, (unsigned int)u << 16);
}

// ---------------- fused preamble: all W -> WT bf16 transposed + edge count ----------------

#define WTOT 108544  // 65536 + 32768 + 8192 + 2048

__global__ void k_pre(const float* __restrict__ Wa, const float* __restrict__ Wb,
                      const float* __restrict__ Wc, const float* __restrict__ Wd,
                      unsigned short* __restrict__ Ta, unsigned short* __restrict__ Tb,
                      unsigned short* __restrict__ Tc, unsigned short* __restrict__ Td,
                      const int* __restrict__ ei, int* __restrict__ cnt, int E, int N) {
    int gid = blockIdx.x * blockDim.x + threadIdx.x;
    if (gid < WTOT) {
        int id = gid;
        const float* W; unsigned short* T; int K, Nc;
        if (id < 65536)       { W = Wa; T = Ta; K = 256; Nc = 256; }
        else if (id < 98304)  { id -= 65536;  W = Wb; T = Tb; K = 256; Nc = 128; }
        else if (id < 106496) { id -= 98304;  W = Wc; T = Tc; K = 128; Nc = 64; }
        else                  { id -= 106496; W = Wd; T = Td; K = 64;  Nc = 32; }
        int n = id / K, k = id % K;
        T[id] = bf16r(W[(long)k * Nc + n]);
        return;
    }
    int e = gid - WTOT;
    if (e >= E + N) return;
    int dst = (e < E) ? ei[E + e] : (e - E);
    atomicAdd(&cnt[dst], 1);
}

// ---------------- CSR scan + scatter ----------------

__global__ void k_scan_blk(const int* __restrict__ cnt, int* __restrict__ offs,
                           int* __restrict__ bsum, int N) {
    __shared__ int temp[1024];
    int t = threadIdx.x;
    int gi = blockIdx.x * 1024 + t;
    int v = (gi < N) ? cnt[gi] : 0;
    temp[t] = v;
    __syncthreads();
    for (int o = 1; o < 1024; o <<= 1) {
        int x = (t >= o) ? temp[t - o] : 0;
        __syncthreads();
        temp[t] += x;
        __syncthreads();
    }
    if (gi < N) offs[gi] = temp[t] - v;
    if (t == 1023) bsum[blockIdx.x] = temp[1023];
}

__global__ void k_scan(const int* __restrict__ cnt, int* __restrict__ offs, int N) {
    __shared__ int temp[1024];
    __shared__ int carry_s;
    int t = threadIdx.x;
    if (t == 0) carry_s = 0;
    __syncthreads();
    for (int base = 0; base < N; base += 1024) {
        int v = (base + t < N) ? cnt[base + t] : 0;
        temp[t] = v;
        __syncthreads();
        for (int o = 1; o < 1024; o <<= 1) {
            int x = (t >= o) ? temp[t - o] : 0;
            __syncthreads();
            temp[t] += x;
            __syncthreads();
        }
        int incl = temp[t];
        int carry = carry_s;
        if (base + t < N) offs[base + t] = carry + incl - v;
        __syncthreads();
        if (t == 1023) carry_s = carry + temp[1023];
        __syncthreads();
    }
    if (t == 0) offs[N] = carry_s;
}

__global__ void k_scan_add(int* __restrict__ offs, const int* __restrict__ bpre,
                           int* __restrict__ wp, int N, int nb) {
    int gi = blockIdx.x * blockDim.x + threadIdx.x;
    if (gi < N) {
        int v = offs[gi] + bpre[gi >> 10];
        offs[gi] = v;
        wp[gi] = v;
    } else if (gi == N) {
        offs[N] = bpre[nb];
    }
}

__global__ void k_scatter(const int* __restrict__ ei, int* __restrict__ wp,
                          int* __restrict__ adj, int E, int N) {
    int e = blockIdx.x * blockDim.x + threadIdx.x;
    if (e >= E + N) return;
    int srcn = (e < E) ? ei[e] : (e - E);
    int dst  = (e < E) ? ei[E + e] : (e - E);
    int pos = atomicAdd(&wp[dst], 1);
    adj[pos] = srcn;
}

// ---------------- MFMA GEMM + fused s/d scores ----------------
// One block = 64 rows x ALL Nc columns (no A re-fetch across column blocks).
// A loaded global->reg ONCE (bf16-converted regs persist); B staged per 64-col
// tile from L2 (weight tile <=131KB stays hot). K-loop barrier-free per tile.

template<int BN, int CT, int KT, bool F32A>
__global__ __launch_bounds__(256) void k_mgemm(const void* __restrict__ Ain,
                                               const unsigned short* __restrict__ WT,
                                               unsigned short* __restrict__ Cb,
                                               const float* __restrict__ a_src,
                                               const float* __restrict__ a_dst,
                                               float* __restrict__ sbuf,
                                               float* __restrict__ dbuf,
                                               int M, int H) {
    constexpr int NC    = BN * CT;       // total output columns
    constexpr int KITER = KT / 32;       // K-steps
    constexpr int KS    = KT + 8;        // B LDS col stride (shorts)
    constexpr int NBF   = BN / 16;       // B fragments per tile per wave
    constexpr int CPR   = NC / 32;       // 32-col chunks per row (epilogue)
    constexpr int SP    = NC + 8;        // epilogue LDS row stride
    constexpr int STAGE = BN * KS;
    constexpr int EPIL  = 64 * SP;
    constexpr int LBSZ  = STAGE > EPIL ? STAGE : EPIL;
    __shared__ __align__(16) unsigned short LB[LBSZ];

    int t = threadIdx.x;
    int wv = t >> 6, l = t & 63;
    int row_in = l & 15, quad = l >> 4;
    int bm = blockIdx.x * 64;

    // ---- load A fragments once (per-lane own fragment), convert to bf16 regs ----
    int grA = min(bm + wv * 16 + row_in, M - 1);
    short8 areg[KITER];
    if constexpr (F32A) {
        const float* Af = (const float*)Ain;
        float4 af0[KITER], af1[KITER];
#pragma unroll
        for (int ki = 0; ki < KITER; ++ki) {
            const float4* p = (const float4*)&Af[(long)grA * KT + ki * 32 + quad * 8];
            af0[ki] = p[0];
            af1[ki] = p[1];
        }
#pragma unroll
        for (int ki = 0; ki < KITER; ++ki) {
            float4 f0 = af0[ki], f1 = af1[ki];
            short8 av;
            av[0] = (short)bf16r(f0.x); av[1] = (short)bf16r(f0.y);
            av[2] = (short)bf16r(f0.z); av[3] = (short)bf16r(f0.w);
            av[4] = (short)bf16r(f1.x); av[5] = (short)bf16r(f1.y);
            av[6] = (short)bf16r(f1.z); av[7] = (short)bf16r(f1.w);
            areg[ki] = av;
        }
    } else {
        const unsigned short* Ab = (const unsigned short*)Ain;
#pragma unroll
        for (int ki = 0; ki < KITER; ++ki)
            areg[ki] = *(const short8*)&Ab[(long)grA * KT + ki * 32 + quad * 8];
    }

    f32x4 acc[CT][NBF];
#pragma unroll
    for (int c = 0; c < CT; ++c)
#pragma unroll
        for (int j = 0; j < NBF; ++j) acc[c][j] = (f32x4){0.f, 0.f, 0.f, 0.f};

    // ---- per column-tile: stage B (L2-hot), MFMA all K ----
    constexpr int PER = BN * (KT / 8) / 256;   // 16B chunks per thread
#pragma unroll
    for (int ct = 0; ct < CT; ++ct) {
        if (ct > 0) __syncthreads();   // protect LDS reuse from previous tile
#pragma unroll
        for (int i = 0; i < PER; ++i) {
            int ch = t + i * 256;
            int col = ch / (KT / 8);
            int kc  = ch % (KT / 8);
            *(short8*)&LB[col * KS + kc * 8] =
                *(const short8*)&WT[(long)(ct * BN + col) * KT + kc * 8];
        }
        __syncthreads();
#pragma unroll
        for (int ki = 0; ki < KITER; ++ki) {
            short8 av = areg[ki];
#pragma unroll
            for (int f = 0; f < NBF; ++f) {
                short8 bv = *(const short8*)&LB[(f * 16 + row_in) * KS + ki * 32 + quad * 8];
                acc[ct][f] = __builtin_amdgcn_mfma_f32_16x16x32_bf16(av, bv, acc[ct][f], 0, 0, 0);
            }
        }
    }
    __syncthreads();   // before LDS reuse for epilogue

    // ---- epilogue: LDS repack (bf16) -> coalesced stores + fused s/d ----
    // C/D layout: col = ct*BN + f*16 + (lane&15), row (in wave tile) = quad*4+reg
#pragma unroll
    for (int r = 0; r < 4; ++r)
#pragma unroll
        for (int ct = 0; ct < CT; ++ct)
#pragma unroll
            for (int f = 0; f < NBF; ++f)
                LB[(wv * 16 + quad * 4 + r) * SP + ct * BN + f * 16 + row_in] =
                    bf16r(acc[ct][f][r]);
    __syncthreads();

    constexpr int TOT = 64 * CPR;   // (row, head-chunk) pairs
    for (int ch = t; ch < TOT; ch += 256) {
        int rr = ch / CPR, cc = ch % CPR;
        int grow = bm + rr;
        if (grow < M) {
            const unsigned short* ep = &LB[rr * SP + cc * 32];
            short8 v0 = *(const short8*)(ep);
            short8 v1 = *(const short8*)(ep + 8);
            short8 v2 = *(const short8*)(ep + 16);
            short8 v3 = *(const short8*)(ep + 24);
            unsigned short* cp = &Cb[(long)grow * NC + cc * 32];
            *(short8*)(cp)      = v0;
            *(short8*)(cp + 8)  = v1;
            *(short8*)(cp + 16) = v2;
            *(short8*)(cp + 24) = v3;
            const float* ap = a_src + cc * 32;   // head = cc (32 channels/head)
            const float* dp = a_dst + cc * 32;
            float ss = 0.f, dd = 0.f;
#pragma unroll
            for (int u = 0; u < 8; ++u) {
                float va = bf2f((unsigned short)v0[u]); ss += va * ap[u];      dd += va * dp[u];
                float vb = bf2f((unsigned short)v1[u]); ss += vb * ap[8 + u];  dd += vb * dp[8 + u];
                float vc = bf2f((unsigned short)v2[u]); ss += vc * ap[16 + u]; dd += vc * dp[16 + u];
                float vd = bf2f((unsigned short)v3[u]); ss += vd * ap[24 + u]; dd += vd * dp[24 + u];
            }
            sbuf[(long)grow * H + cc] = ss;
            dbuf[(long)grow * H + cc] = dd;
        }
    }
}

// ---------------- fused aggregate: max-free softmax, single pass ----------------
// one thread per (node, head, c/8). ACT=1: elu -> bf16 out (next GEMM input).
// ACT=0: final layer (H==1) -> log_softmax via quad shuffles -> fp32 d_out.

template<int ACT>
__global__ void k_aggf(const unsigned short* __restrict__ h, const float* __restrict__ s,
                       const float* __restrict__ dsc, const int* __restrict__ offs,
                       const int* __restrict__ adj, const float* __restrict__ bias,
                       unsigned short* __restrict__ out16, float* __restrict__ out32,
                       int N, int H) {
    const int C8 = 4;
    long tid = (long)blockIdx.x * blockDim.x + threadIdx.x;
    int HC8 = H * C8;
    if (tid >= (long)N * HC8) return;
    int c8 = (int)(tid % C8);
    int hh = (int)((tid / C8) % H);
    int n  = (int)(tid / HC8);
    int beg = offs[n], end = offs[n + 1];
    float dn = dsc[n * H + hh];
    int HC = HC8 * 8;
    int coff = hh * 32 + c8 * 8;

    float denom = 0.f;
    float acc[8];
#pragma unroll
    for (int u = 0; u < 8; ++u) acc[u] = 0.f;

    for (int j = beg; j < end; ++j) {
        int sn = adj[j];
        float e = s[sn * H + hh] + dn;
        e = e > 0.f ? e : LRELU_SLOPE * e;
        float w = __expf(fminf(e, 80.f));
        short8 hv = *(const short8*)(h + (size_t)sn * HC + coff);
        denom += w;
#pragma unroll
        for (int u = 0; u < 8; ++u)
            acc[u] += w * bf2f((unsigned short)hv[u]);
    }

    float inv = 1.0f / denom;
    float o[8];
#pragma unroll
    for (int u = 0; u < 8; ++u) o[u] = acc[u] * inv + bias[coff + u];

    if (ACT == 1) {
        short8 pk;
#pragma unroll
        for (int u = 0; u < 8; ++u) {
            float v = o[u] > 0.f ? o[u] : (__expf(o[u]) - 1.f);
            pk[u] = (short)bf16r(v);
        }
        *(short8*)(out16 + tid * 8) = pk;
    } else {
        float m = o[0];
#pragma unroll
        for (int u = 1; u < 8; ++u) m = fmaxf(m, o[u]);
        m = fmaxf(m, __shfl_xor(m, 1));
        m = fmaxf(m, __shfl_xor(m, 2));
        float ssum = 0.f;
#pragma unroll
        for (int u = 0; u < 8; ++u) ssum += __expf(o[u] - m);
        ssum += __shfl_xor(ssum, 1);
        ssum += __shfl_xor(ssum, 2);
        float lse = m + __logf(ssum);
        float4 lo = {o[0] - lse, o[1] - lse, o[2] - lse, o[3] - lse};
        float4 hi = {o[4] - lse, o[5] - lse, o[6] - lse, o[7] - lse};
        *(float4*)(out32 + tid * 8)     = lo;
        *(float4*)(out32 + tid * 8 + 4) = hi;
    }
}

// ---------------- host ----------------

static inline size_t align_up(size_t x) { return (x + 255) & ~(size_t)255; }

extern "C" void kernel_launch(void* const* d_in, const int* in_sizes, int n_in,
                              void* d_out, int out_size, void* d_ws, size_t ws_size,
                              hipStream_t stream) {
    const float* x   = (const float*)d_in[0];
    const int*   ei  = (const int*)d_in[1];

    const int N = in_sizes[0] / 256;   // 50000
    const int E = in_sizes[1] / 2;     // 400000
    const int ET = E + N;
    const int NB = (N + 1023) / 1024;

    size_t off = 0;
    char* ws = (char*)d_ws;
    auto take = [&](size_t bytes) { char* p = ws + off; off += align_up(bytes); return p; };
    int*   offs  = (int*)take((size_t)(N + 1) * 4);
    int*   wp    = (int*)take((size_t)N * 4);
    int*   adj   = (int*)take((size_t)ET * 4);
    int*   bsum  = (int*)take((size_t)(NB + 1) * 4);
    int*   bpre  = (int*)take((size_t)(NB + 1) * 4);
    float* sbuf  = (float*)take((size_t)N * 8 * 4);
    float* dbuf  = (float*)take((size_t)N * 8 * 4);
    unsigned short* Xb = (unsigned short*)take((size_t)N * 256 * 2);  // activations (bf16)
    unsigned short* Yb = (unsigned short*)take((size_t)N * 256 * 2);  // h (GEMM out, bf16)
    unsigned short* WT0 = (unsigned short*)take((size_t)256 * 256 * 2);
    unsigned short* WT1 = (unsigned short*)take((size_t)256 * 128 * 2);
    unsigned short* WT2 = (unsigned short*)take((size_t)128 * 64 * 2);
    unsigned short* WT3 = (unsigned short*)take((size_t)64 * 32 * 2);
    (void)ws_size;

    // ---- preamble + CSR build ----
    hipMemsetAsync(wp, 0, (size_t)N * 4, stream);
    {
        long tot = WTOT + ET;
        k_pre<<<(int)((tot + 255) / 256), 256, 0, stream>>>(
            (const float*)d_in[2], (const float*)d_in[6], (const float*)d_in[10],
            (const float*)d_in[14], WT0, WT1, WT2, WT3, ei, wp, E, N);
        k_scan_blk<<<NB, 1024, 0, stream>>>(wp, offs, bsum, N);
        k_scan<<<1, 1024, 0, stream>>>(bsum, bpre, NB);
        k_scan_add<<<(N + 256) / 256, 256, 0, stream>>>(offs, bpre, wp, N, NB);
        k_scatter<<<(ET + 255) / 256, 256, 0, stream>>>(ei, wp, adj, E, N);
    }

    const float* as_[4] = {(const float*)d_in[3], (const float*)d_in[7],
                           (const float*)d_in[11], (const float*)d_in[15]};
    const float* ad_[4] = {(const float*)d_in[4], (const float*)d_in[8],
                           (const float*)d_in[12], (const float*)d_in[16]};
    const float* b_[4]  = {(const float*)d_in[5], (const float*)d_in[9],
                           (const float*)d_in[13], (const float*)d_in[17]};
    int H_[4] = {8, 4, 2, 1};

    int gy = (N + 63) / 64;
    for (int li = 0; li < 4; ++li) {
        int H = H_[li];

        // GEMM + fused s/d: one block = 64 rows x all columns (A fetched once)
        if (li == 0) {
            k_mgemm<64, 4, 256, true><<<gy, 256, 0, stream>>>(
                x, WT0, Yb, as_[0], ad_[0], sbuf, dbuf, N, H);
        } else if (li == 1) {
            k_mgemm<64, 2, 256, false><<<gy, 256, 0, stream>>>(
                Xb, WT1, Yb, as_[1], ad_[1], sbuf, dbuf, N, H);
        } else if (li == 2) {
            k_mgemm<64, 1, 128, false><<<gy, 256, 0, stream>>>(
                Xb, WT2, Yb, as_[2], ad_[2], sbuf, dbuf, N, H);
        } else {
            k_mgemm<32, 1, 64, false><<<gy, 256, 0, stream>>>(
                Xb, WT3, Yb, as_[3], ad_[3], sbuf, dbuf, N, H);
        }
        // aggregate (+elu->bf16 for layers 0-2; +log_softmax->d_out for layer 3)
        {
            long total = (long)N * H * 4;
            int nb = (int)((total + 255) / 256);
            if (li < 3)
                k_aggf<1><<<nb, 256, 0, stream>>>(Yb, sbuf, dbuf, offs, adj, b_[li],
                                                  Xb, nullptr, N, H);
            else
                k_aggf<0><<<nb, 256, 0, stream>>>(Yb, sbuf, dbuf, offs, adj, b_[li],
                                                  nullptr, (float*)d_out, N, H);
        }
    }
}

// Round 13
// 338.571 us; speedup vs baseline: 1.0591x; 1.0591x over previous
//
#include <hip/hip_runtime.h>
#include <hip/hip_bf16.h>

#define LRELU_SLOPE 0.2f

typedef __attribute__((ext_vector_type(8))) short short8;
typedef __attribute__((ext_vector_type(4))) float f32x4;

__device__ __forceinline__ unsigned short bf16r(float f) {
    unsigned int u = __builtin_bit_cast(unsigned int, f);
    u += 0x7fffu + ((u >> 16) & 1u);   // RNE
    return (unsigned short)(u >> 16);
}
__device__ __forceinline__ float bf2f(unsigned short u) {
    return __builtin_bit_cast(float, (unsigned int)u << 16);
}

// ---------------- fused preamble: all W -> WT bf16 transposed + edge count ----------------

#define WTOT 108544  // 65536 + 32768 + 8192 + 2048

__global__ void k_pre(const float* __restrict__ Wa, const float* __restrict__ Wb,
                      const float* __restrict__ Wc, const float* __restrict__ Wd,
                      unsigned short* __restrict__ Ta, unsigned short* __restrict__ Tb,
                      unsigned short* __restrict__ Tc, unsigned short* __restrict__ Td,
                      const int* __restrict__ ei, int* __restrict__ cnt, int E, int N) {
    int gid = blockIdx.x * blockDim.x + threadIdx.x;
    if (gid < WTOT) {
        int id = gid;
        const float* W; unsigned short* T; int K, Nc;
        if (id < 65536)       { W = Wa; T = Ta; K = 256; Nc = 256; }
        else if (id < 98304)  { id -= 65536;  W = Wb; T = Tb; K = 256; Nc = 128; }
        else if (id < 106496) { id -= 98304;  W = Wc; T = Tc; K = 128; Nc = 64; }
        else                  { id -= 106496; W = Wd; T = Td; K = 64;  Nc = 32; }
        int n = id / K, k = id % K;
        T[id] = bf16r(W[(long)k * Nc + n]);
        return;
    }
    int e = gid - WTOT;
    if (e >= E + N) return;
    int dst = (e < E) ? ei[E + e] : (e - E);
    atomicAdd(&cnt[dst], 1);
}

// ---------------- CSR scan + scatter ----------------

__global__ void k_scan_blk(const int* __restrict__ cnt, int* __restrict__ offs,
                           int* __restrict__ bsum, int N) {
    __shared__ int temp[1024];
    int t = threadIdx.x;
    int gi = blockIdx.x * 1024 + t;
    int v = (gi < N) ? cnt[gi] : 0;
    temp[t] = v;
    __syncthreads();
    for (int o = 1; o < 1024; o <<= 1) {
        int x = (t >= o) ? temp[t - o] : 0;
        __syncthreads();
        temp[t] += x;
        __syncthreads();
    }
    if (gi < N) offs[gi] = temp[t] - v;
    if (t == 1023) bsum[blockIdx.x] = temp[1023];
}

__global__ void k_scan(const int* __restrict__ cnt, int* __restrict__ offs, int N) {
    __shared__ int temp[1024];
    __shared__ int carry_s;
    int t = threadIdx.x;
    if (t == 0) carry_s = 0;
    __syncthreads();
    for (int base = 0; base < N; base += 1024) {
        int v = (base + t < N) ? cnt[base + t] : 0;
        temp[t] = v;
        __syncthreads();
        for (int o = 1; o < 1024; o <<= 1) {
            int x = (t >= o) ? temp[t - o] : 0;
            __syncthreads();
            temp[t] += x;
            __syncthreads();
        }
        int incl = temp[t];
        int carry = carry_s;
        if (base + t < N) offs[base + t] = carry + incl - v;
        __syncthreads();
        if (t == 1023) carry_s = carry + temp[1023];
        __syncthreads();
    }
    if (t == 0) offs[N] = carry_s;
}

__global__ void k_scan_add(int* __restrict__ offs, const int* __restrict__ bpre,
                           int* __restrict__ wp, int N, int nb) {
    int gi = blockIdx.x * blockDim.x + threadIdx.x;
    if (gi < N) {
        int v = offs[gi] + bpre[gi >> 10];
        offs[gi] = v;
        wp[gi] = v;
    } else if (gi == N) {
        offs[N] = bpre[nb];
    }
}

__global__ void k_scatter(const int* __restrict__ ei, int* __restrict__ wp,
                          int* __restrict__ adj, int E, int N) {
    int e = blockIdx.x * blockDim.x + threadIdx.x;
    if (e >= E + N) return;
    int srcn = (e < E) ? ei[e] : (e - E);
    int dst  = (e < E) ? ei[E + e] : (e - E);
    int pos = atomicAdd(&wp[dst], 1);
    adj[pos] = srcn;
}

// ---------------- MFMA GEMM + fused s/d scores (r11 structure + XCD swizzle) ----------------
// Per-wave 16xBN tile; block = 64 rows x BN cols. B staged in LDS once (whole K),
// A-frags global->reg upfront (deep MLP). Barrier-free K loop.
// XCD swizzle: the GX column-tiles of one row-group get block ids differing by 8
// -> same XCD (id%8 round-robin) -> A rows fetched from HBM once, then L2-hit.

template<int BN, int KT, int GX, bool F32A>
__global__ __launch_bounds__(256) void k_mgemm(const void* __restrict__ Ain,
                                               const unsigned short* __restrict__ WT,
                                               unsigned short* __restrict__ Cb,
                                               const float* __restrict__ a_src,
                                               const float* __restrict__ a_dst,
                                               float* __restrict__ sbuf,
                                               float* __restrict__ dbuf,
                                               int M, int Nc, int H, int RB) {
    constexpr int KITER = KT / 32;       // K-steps
    constexpr int KS  = KT + 8;          // B LDS col stride (shorts)
    constexpr int NBF = BN / 16;         // B fragments per wave
    constexpr int CPR = BN / 32;         // 32-col chunks per row (epilogue)
    constexpr int SP  = BN + 8;          // epilogue LDS row stride
    constexpr int STAGE = BN * KS;
    constexpr int EPIL  = 64 * SP;
    constexpr int LBSZ  = STAGE > EPIL ? STAGE : EPIL;
    __shared__ __align__(16) unsigned short LB[LBSZ];

    // swizzled decode: id = xcd + 8*( (rb/8)*GX + ct ), rb = (q/GX)*8 + xcd
    int id = blockIdx.x;
    int xcd = id & 7;
    int q  = id >> 3;
    int ct = q % GX;
    int rb = (q / GX) * 8 + xcd;
    if (rb >= RB) return;
    int bm = rb * 64, bn = ct * BN;

    int t = threadIdx.x;
    int wv = t >> 6, l = t & 63;
    int row_in = l & 15, quad = l >> 4;

    // ---- issue ALL A-frag loads upfront (per-lane own fragment) ----
    int grA = min(bm + wv * 16 + row_in, M - 1);
    const float* Af = (const float*)Ain;
    const unsigned short* Ab = (const unsigned short*)Ain;
    float4 af0[KITER], af1[KITER];
    short8 areg[KITER];
    if constexpr (F32A) {
#pragma unroll
        for (int ki = 0; ki < KITER; ++ki) {
            const float4* p = (const float4*)&Af[(long)grA * KT + ki * 32 + quad * 8];
            af0[ki] = p[0];
            af1[ki] = p[1];
        }
    } else {
#pragma unroll
        for (int ki = 0; ki < KITER; ++ki)
            areg[ki] = *(const short8*)&Ab[(long)grA * KT + ki * 32 + quad * 8];
    }

    // ---- cooperative B stage (whole K), single barrier ----
    constexpr int PER = BN * (KT / 8) / 256;   // 16B chunks per thread (>=1)
#pragma unroll
    for (int i = 0; i < PER; ++i) {
        int ch = t + i * 256;
        int col = ch / (KT / 8);
        int kc  = ch % (KT / 8);
        int gcol = min(bn + col, Nc - 1);
        *(short8*)&LB[col * KS + kc * 8] = *(const short8*)&WT[(long)gcol * KT + kc * 8];
    }
    __syncthreads();

    f32x4 acc[NBF];
#pragma unroll
    for (int j = 0; j < NBF; ++j) acc[j] = (f32x4){0.f, 0.f, 0.f, 0.f};

    // ---- K loop: no barriers, B from LDS, A from prefetched regs ----
#pragma unroll
    for (int ki = 0; ki < KITER; ++ki) {
        short8 av;
        if constexpr (F32A) {
            float4 f0 = af0[ki], f1 = af1[ki];
            av[0] = (short)bf16r(f0.x); av[1] = (short)bf16r(f0.y);
            av[2] = (short)bf16r(f0.z); av[3] = (short)bf16r(f0.w);
            av[4] = (short)bf16r(f1.x); av[5] = (short)bf16r(f1.y);
            av[6] = (short)bf16r(f1.z); av[7] = (short)bf16r(f1.w);
        } else {
            av = areg[ki];
        }
#pragma unroll
        for (int f = 0; f < NBF; ++f) {
            short8 bv = *(const short8*)&LB[(f * 16 + row_in) * KS + ki * 32 + quad * 8];
            acc[f] = __builtin_amdgcn_mfma_f32_16x16x32_bf16(av, bv, acc[f], 0, 0, 0);
        }
    }
    __syncthreads();   // before LDS reuse for epilogue

    // ---- epilogue: LDS repack (bf16) -> coalesced stores + fused s/d ----
#pragma unroll
    for (int r = 0; r < 4; ++r)
#pragma unroll
        for (int f = 0; f < NBF; ++f)
            LB[(wv * 16 + quad * 4 + r) * SP + f * 16 + row_in] = bf16r(acc[f][r]);
    __syncthreads();

    int rr = t / CPR, cc = t % CPR;
    if (rr < 64) {
        int grow = bm + rr;
        int colb = bn + cc * 32;
        if (grow < M && colb < Nc) {
            const unsigned short* ep = &LB[rr * SP + cc * 32];
            short8 v0 = *(const short8*)(ep);
            short8 v1 = *(const short8*)(ep + 8);
            short8 v2 = *(const short8*)(ep + 16);
            short8 v3 = *(const short8*)(ep + 24);
            unsigned short* cp = &Cb[(long)grow * Nc + colb];
            *(short8*)(cp)      = v0;
            *(short8*)(cp + 8)  = v1;
            *(short8*)(cp + 16) = v2;
            *(short8*)(cp + 24) = v3;
            int hd = colb >> 5;   // 32 channels per head
            const float* ap = a_src + hd * 32;
            const float* dp = a_dst + hd * 32;
            float ss = 0.f, dd = 0.f;
#pragma unroll
            for (int u = 0; u < 8; ++u) {
                float va = bf2f((unsigned short)v0[u]); ss += va * ap[u];      dd += va * dp[u];
                float vb = bf2f((unsigned short)v1[u]); ss += vb * ap[8 + u];  dd += vb * dp[8 + u];
                float vc = bf2f((unsigned short)v2[u]); ss += vc * ap[16 + u]; dd += vc * dp[16 + u];
                float vd = bf2f((unsigned short)v3[u]); ss += vd * ap[24 + u]; dd += vd * dp[24 + u];
            }
            sbuf[(long)grow * H + hd] = ss;
            dbuf[(long)grow * H + hd] = dd;
        }
    }
}

// ---------------- fused aggregate: max-free softmax, single pass ----------------
// one thread per (node, head, c/8). ACT=1: elu -> bf16 out (next GEMM input).
// ACT=0: final layer (H==1) -> log_softmax via quad shuffles -> fp32 d_out.

template<int ACT>
__global__ void k_aggf(const unsigned short* __restrict__ h, const float* __restrict__ s,
                       const float* __restrict__ dsc, const int* __restrict__ offs,
                       const int* __restrict__ adj, const float* __restrict__ bias,
                       unsigned short* __restrict__ out16, float* __restrict__ out32,
                       int N, int H) {
    const int C8 = 4;
    long tid = (long)blockIdx.x * blockDim.x + threadIdx.x;
    int HC8 = H * C8;
    if (tid >= (long)N * HC8) return;
    int c8 = (int)(tid % C8);
    int hh = (int)((tid / C8) % H);
    int n  = (int)(tid / HC8);
    int beg = offs[n], end = offs[n + 1];
    float dn = dsc[n * H + hh];
    int HC = HC8 * 8;
    int coff = hh * 32 + c8 * 8;

    float denom = 0.f;
    float acc[8];
#pragma unroll
    for (int u = 0; u < 8; ++u) acc[u] = 0.f;

    for (int j = beg; j < end; ++j) {
        int sn = adj[j];
        float e = s[sn * H + hh] + dn;
        e = e > 0.f ? e : LRELU_SLOPE * e;
        float w = __expf(fminf(e, 80.f));
        short8 hv = *(const short8*)(h + (size_t)sn * HC + coff);
        denom += w;
#pragma unroll
        for (int u = 0; u < 8; ++u)
            acc[u] += w * bf2f((unsigned short)hv[u]);
    }

    float inv = 1.0f / denom;
    float o[8];
#pragma unroll
    for (int u = 0; u < 8; ++u) o[u] = acc[u] * inv + bias[coff + u];

    if (ACT == 1) {
        short8 pk;
#pragma unroll
        for (int u = 0; u < 8; ++u) {
            float v = o[u] > 0.f ? o[u] : (__expf(o[u]) - 1.f);
            pk[u] = (short)bf16r(v);
        }
        *(short8*)(out16 + tid * 8) = pk;
    } else {
        float m = o[0];
#pragma unroll
        for (int u = 1; u < 8; ++u) m = fmaxf(m, o[u]);
        m = fmaxf(m, __shfl_xor(m, 1));
        m = fmaxf(m, __shfl_xor(m, 2));
        float ssum = 0.f;
#pragma unroll
        for (int u = 0; u < 8; ++u) ssum += __expf(o[u] - m);
        ssum += __shfl_xor(ssum, 1);
        ssum += __shfl_xor(ssum, 2);
        float lse = m + __logf(ssum);
        float4 lo = {o[0] - lse, o[1] - lse, o[2] - lse, o[3] - lse};
        float4 hi = {o[4] - lse, o[5] - lse, o[6] - lse, o[7] - lse};
        *(float4*)(out32 + tid * 8)     = lo;
        *(float4*)(out32 + tid * 8 + 4) = hi;
    }
}

// ---------------- host ----------------

static inline size_t align_up(size_t x) { return (x + 255) & ~(size_t)255; }

extern "C" void kernel_launch(void* const* d_in, const int* in_sizes, int n_in,
                              void* d_out, int out_size, void* d_ws, size_t ws_size,
                              hipStream_t stream) {
    const float* x   = (const float*)d_in[0];
    const int*   ei  = (const int*)d_in[1];

    const int N = in_sizes[0] / 256;   // 50000
    const int E = in_sizes[1] / 2;     // 400000
    const int ET = E + N;
    const int NB = (N + 1023) / 1024;

    size_t off = 0;
    char* ws = (char*)d_ws;
    auto take = [&](size_t bytes) { char* p = ws + off; off += align_up(bytes); return p; };
    int*   offs  = (int*)take((size_t)(N + 1) * 4);
    int*   wp    = (int*)take((size_t)N * 4);
    int*   adj   = (int*)take((size_t)ET * 4);
    int*   bsum  = (int*)take((size_t)(NB + 1) * 4);
    int*   bpre  = (int*)take((size_t)(NB + 1) * 4);
    float* sbuf  = (float*)take((size_t)N * 8 * 4);
    float* dbuf  = (float*)take((size_t)N * 8 * 4);
    unsigned short* Xb = (unsigned short*)take((size_t)N * 256 * 2);  // activations (bf16)
    unsigned short* Yb = (unsigned short*)take((size_t)N * 256 * 2);  // h (GEMM out, bf16)
    unsigned short* WT0 = (unsigned short*)take((size_t)256 * 256 * 2);
    unsigned short* WT1 = (unsigned short*)take((size_t)256 * 128 * 2);
    unsigned short* WT2 = (unsigned short*)take((size_t)128 * 64 * 2);
    unsigned short* WT3 = (unsigned short*)take((size_t)64 * 32 * 2);
    (void)ws_size;

    // ---- preamble + CSR build ----
    hipMemsetAsync(wp, 0, (size_t)N * 4, stream);
    {
        long tot = WTOT + ET;
        k_pre<<<(int)((tot + 255) / 256), 256, 0, stream>>>(
            (const float*)d_in[2], (const float*)d_in[6], (const float*)d_in[10],
            (const float*)d_in[14], WT0, WT1, WT2, WT3, ei, wp, E, N);
        k_scan_blk<<<NB, 1024, 0, stream>>>(wp, offs, bsum, N);
        k_scan<<<1, 1024, 0, stream>>>(bsum, bpre, NB);
        k_scan_add<<<(N + 256) / 256, 256, 0, stream>>>(offs, bpre, wp, N, NB);
        k_scatter<<<(ET + 255) / 256, 256, 0, stream>>>(ei, wp, adj, E, N);
    }

    const float* as_[4] = {(const float*)d_in[3], (const float*)d_in[7],
                           (const float*)d_in[11], (const float*)d_in[15]};
    const float* ad_[4] = {(const float*)d_in[4], (const float*)d_in[8],
                           (const float*)d_in[12], (const float*)d_in[16]};
    const float* b_[4]  = {(const float*)d_in[5], (const float*)d_in[9],
                           (const float*)d_in[13], (const float*)d_in[17]};
    int H_[4] = {8, 4, 2, 1};

    const int RB  = (N + 63) / 64;         // row blocks (782)
    const int RBp = ((RB + 7) / 8) * 8;    // padded to 8 for swizzle (784)

    for (int li = 0; li < 4; ++li) {
        int H = H_[li];

        // GEMM + fused s/d (r11 structure + XCD swizzle)
        if (li == 0) {
            k_mgemm<64, 256, 4, true><<<4 * RBp, 256, 0, stream>>>(
                x, WT0, Yb, as_[0], ad_[0], sbuf, dbuf, N, 256, H, RB);
        } else if (li == 1) {
            k_mgemm<64, 256, 2, false><<<2 * RBp, 256, 0, stream>>>(
                Xb, WT1, Yb, as_[1], ad_[1], sbuf, dbuf, N, 128, H, RB);
        } else if (li == 2) {
            k_mgemm<64, 128, 1, false><<<RBp, 256, 0, stream>>>(
                Xb, WT2, Yb, as_[2], ad_[2], sbuf, dbuf, N, 64, H, RB);
        } else {
            k_mgemm<32, 64, 1, false><<<RBp, 256, 0, stream>>>(
                Xb, WT3, Yb, as_[3], ad_[3], sbuf, dbuf, N, 32, H, RB);
        }
        // aggregate (+elu->bf16 for layers 0-2; +log_softmax->d_out for layer 3)
        {
            long total = (long)N * H * 4;
            int nb = (int)((total + 255) / 256);
            if (li < 3)
                k_aggf<1><<<nb, 256, 0, stream>>>(Yb, sbuf, dbuf, offs, adj, b_[li],
                                                  Xb, nullptr, N, H);
            else
                k_aggf<0><<<nb, 256, 0, stream>>>(Yb, sbuf, dbuf, offs, adj, b_[li],
                                                  nullptr, (float*)d_out, N, H);
        }
    }
}